// Round 2
// baseline (378.501 us; speedup 1.0000x reference)
//
#include <hip/hip_runtime.h>

// NPLinear: 3 layers, B=2, C=CO=16
// NIN  = {512,1024,1024}, NOUT = {1024,1024,512}
// out = [out_w0, out_w1, out_w2, out_b0, out_b1, out_b2] flat fp32

typedef float f4 __attribute__((ext_vector_type(4)));

__device__ __forceinline__ float wave_red64(float s) {
  #pragma unroll
  for (int m = 1; m < 64; m <<= 1) s += __shfl_xor(s, m, 64);
  return s;
}

// ---------------------------------------------------------------------------
// K0: zero the atomic row-sum accumulators (replaces hipMemsetAsync's
// fillBufferAligned, which measured 155 us for 320 KB). 80 blocks x 256 f4.
__global__ __launch_bounds__(256) void k0_zero(float* __restrict__ p) {
  f4* p4 = (f4*)p;
  p4[blockIdx.x * 256 + threadIdx.x] = (f4){0.f, 0.f, 0.f, 0.f};
}

// ---------------------------------------------------------------------------
// K1: fused row/col sums of all three W tensors.
// Block = 256 threads, handles 32 rows of one (b,c) slice.
// col_sum (per-row sum over n_in): wave reduce -> LDS -> direct store.
// row_sum (per-col sum over n_out): per-thread f4 accumulator -> atomicAdd.
// Grid: L0 32x32=1024 blocks, L1 1024, L2 32x16=512 -> 2560.
__global__ __launch_bounds__(256) void k1_reduce(
    const float* __restrict__ w0, const float* __restrict__ w1, const float* __restrict__ w2,
    float* __restrict__ rs0, float* __restrict__ rs1, float* __restrict__ rs2,
    float* __restrict__ cs0, float* __restrict__ cs1, float* __restrict__ cs2) {
  __shared__ float part[32][4];
  const int bid = blockIdx.x, t = threadIdx.x;
  int l, rb;
  if (bid < 1024)      { l = 0; rb = bid; }
  else if (bid < 2048) { l = 1; rb = bid - 1024; }
  else                 { l = 2; rb = bid - 2048; }
  const float* w = (l == 0) ? w0 : (l == 1) ? w1 : w2;
  float* rs = (l == 0) ? rs0 : (l == 1) ? rs1 : rs2;
  float* cs = (l == 0) ? cs0 : (l == 1) ? cs1 : cs2;
  const int nout = (l == 2) ? 512 : 1024;
  const int nin  = (l == 0) ? 512 : 1024;
  const int log_chunks = (l == 2) ? 4 : 5;       // nout/32 chunks per slice
  const int slice = rb >> log_chunks;            // b*16+c in [0,32)
  const int chunk = rb & ((1 << log_chunks) - 1);
  const int v4  = nin >> 2;                      // 128 or 256 float4 per row
  const int c4  = t & (v4 - 1);
  const int ro  = t / v4;                        // 0 (v4=256) or 0/1 (v4=128)
  const int rpi = 256 / v4;                      // rows per iteration
  const int wid = t >> 6, lane = t & 63;

  if (t < 128) part[t >> 2][t & 3] = 0.f;
  __syncthreads();

  const f4* wp = (const f4*)w;
  int base = (slice * nout + chunk * 32 + ro) * v4 + c4;
  f4 cacc = {0.f, 0.f, 0.f, 0.f};
  for (int it = 0; it < 32; it += rpi) {
    f4 v = wp[base];
    base += 256;                                 // rpi * v4 == 256 always
    cacc += v;
    float s = v[0] + v[1] + v[2] + v[3];
    s = wave_red64(s);
    if (lane == 0) part[it + ro][wid] = s;       // waves never straddle rows
  }
  __syncthreads();
  if (t < 32)
    cs[slice * nout + chunk * 32 + t] = part[t][0] + part[t][1] + part[t][2] + part[t][3];

  float* rsb = rs + slice * nin + c4 * 4;
  unsafeAtomicAdd(rsb + 0, cacc[0]);
  unsafeAtomicAdd(rsb + 1, cacc[1]);
  unsafeAtomicAdd(rsb + 2, cacc[2]);
  unsafeAtomicAdd(rsb + 3, cacc[3]);
}

// ---------------------------------------------------------------------------
// K2: bias means + rc means. 96 blocks, one per (i,b,c).
__global__ __launch_bounds__(256) void k2_means(
    const float* __restrict__ b0, const float* __restrict__ b1, const float* __restrict__ b2,
    const float* __restrict__ cs0, const float* __restrict__ cs1, const float* __restrict__ cs2,
    float* __restrict__ b_mean, float* __restrict__ rc_mean) {
  const int bid = blockIdx.x, t = threadIdx.x;
  const int i = bid >> 5, b = (bid >> 4) & 1, c = bid & 15;
  const int nout = (i == 2) ? 512 : 1024;
  const int nin  = (i == 0) ? 512 : 1024;
  const float* bias = (i == 0) ? b0 : (i == 1) ? b1 : b2;
  const float* cs   = (i == 0) ? cs0 : (i == 1) ? cs1 : cs2;
  const int rowoff = (b * 16 + c) * nout;
  float s1 = 0.f, s2 = 0.f;
  for (int j = t; j < nout; j += 256) { s1 += bias[rowoff + j]; s2 += cs[rowoff + j]; }
  s1 = wave_red64(s1);
  s2 = wave_red64(s2);
  __shared__ float p1[4], p2[4];
  if ((t & 63) == 0) { p1[t >> 6] = s1; p2[t >> 6] = s2; }
  __syncthreads();
  if (t == 0) {
    float t1 = p1[0] + p1[1] + p1[2] + p1[3];
    float t2 = p2[0] + p2[1] + p2[2] + p2[3];
    b_mean[(i * 2 + b) * 16 + c]  = t1 / (float)nout;
    rc_mean[(i * 2 + b) * 16 + c] = t2 / ((float)nout * (float)nin);
  }
}

// ---------------------------------------------------------------------------
// K3: wb = [rc_means | b_means], then rcz/brcz tiny GEMMs. Single block.
__global__ __launch_bounds__(256) void k3_wb(
    const float* __restrict__ rcw0, const float* __restrict__ rcw1, const float* __restrict__ rcw2,
    const float* __restrict__ rcb0, const float* __restrict__ rcb1, const float* __restrict__ rcb2,
    const float* __restrict__ brcw0, const float* __restrict__ brcw1, const float* __restrict__ brcw2,
    const float* __restrict__ brcb0, const float* __restrict__ brcb1, const float* __restrict__ brcb2,
    const float* __restrict__ b_mean, const float* __restrict__ rc_mean,
    float* __restrict__ rcz, float* __restrict__ brcz) {
  __shared__ float wbs[192];
  const int t = threadIdx.x;
  if (t < 192) {
    int b = t / 96, jj = t % 96;
    float v;
    if (jj < 48) v = rc_mean[((jj >> 4) * 2 + b) * 16 + (jj & 15)];
    else { int j2 = jj - 48; v = b_mean[((j2 >> 4) * 2 + b) * 16 + (j2 & 15)]; }
    wbs[t] = v;
  }
  __syncthreads();
  if (t < 96) {
    const int i = t >> 5, b = (t >> 4) & 1, o = t & 15;
    const float* rcw  = (i == 0) ? rcw0  : (i == 1) ? rcw1  : rcw2;
    const float* rcb  = (i == 0) ? rcb0  : (i == 1) ? rcb1  : rcb2;
    const float* brcw = (i == 0) ? brcw0 : (i == 1) ? brcw1 : brcw2;
    const float* brcb = (i == 0) ? brcb0 : (i == 1) ? brcb1 : brcb2;
    float s1 = rcb[o], s2 = brcb[o];
    const float* wbp = wbs + b * 96;
    for (int j = 0; j < 96; ++j) {
      s1 += wbp[j] * rcw[o * 96 + j];
      s2 += wbp[j] * brcw[o * 96 + j];
    }
    rcz[(i * 2 + b) * 16 + o]  = s1;
    brcz[(i * 2 + b) * 16 + o] = s2;
  }
}

// ---------------------------------------------------------------------------
// K4: rowz[l][b,o,wi] = rb[o] + sum_c rw[o,c]*rcat[b,c,wi]  (z3)
// rcat: row_means[l] | col_means[l-1] | biases[l-1]
// Threads: B*(512+1024+1024)=5120 -> 20 blocks.
__global__ __launch_bounds__(256) void k4_rowz(
    const float* __restrict__ rs0, const float* __restrict__ rs1, const float* __restrict__ rs2,
    const float* __restrict__ cs0, const float* __restrict__ cs1,
    const float* __restrict__ bias0, const float* __restrict__ bias1,
    const float* __restrict__ rw0, const float* __restrict__ rw1, const float* __restrict__ rw2,
    const float* __restrict__ rb0, const float* __restrict__ rb1, const float* __restrict__ rb2,
    float* __restrict__ rowz0, float* __restrict__ rowz1, float* __restrict__ rowz2) {
  const int gid = blockIdx.x * 256 + threadIdx.x;
  int l, rem;
  if (gid < 1024)      { l = 0; rem = gid; }
  else if (gid < 3072) { l = 1; rem = gid - 1024; }
  else                 { l = 2; rem = gid - 3072; }
  const int lnin = (l == 0) ? 9 : 10;
  const int nin  = 1 << lnin;
  const int nout = (l == 2) ? 512 : 1024;
  const int b  = rem >> lnin;
  const int wi = rem & (nin - 1);
  const float* rs = (l == 0) ? rs0 : (l == 1) ? rs1 : rs2;
  float src[48];
  const float inv_nout = 1.f / (float)nout;
  for (int c = 0; c < 16; ++c) src[c] = rs[(b * 16 + c) * nin + wi] * inv_nout;
  int rin = 16;
  if (l > 0) {
    rin = 48;
    const float* csm = (l == 1) ? cs0 : cs1;           // col sums of layer l-1 (len nin)
    const float* bm  = (l == 1) ? bias0 : bias1;
    const float inv_nin_prev = (l == 1) ? (1.f / 512.f) : (1.f / 1024.f);
    for (int c = 0; c < 16; ++c) {
      src[16 + c] = csm[(b * 16 + c) * nin + wi] * inv_nin_prev;
      src[32 + c] = bm[(b * 16 + c) * nin + wi];
    }
  }
  const float* rw = (l == 0) ? rw0 : (l == 1) ? rw1 : rw2;
  const float* rb = (l == 0) ? rb0 : (l == 1) ? rb1 : rb2;
  float* rowz = (l == 0) ? rowz0 : (l == 1) ? rowz1 : rowz2;
  for (int o = 0; o < 16; ++o) {
    float s = rb[o];
    for (int c = 0; c < rin; ++c) s += rw[o * rin + c] * src[c];
    rowz[(b * 16 + o) * nin + wi] = s;
  }
}

// ---------------------------------------------------------------------------
// K5: colz[l][b,o,h] = cb[o]+Lb[o]+rcz[b,o] + sum_c cw[o,c]*ccat[b,c,h]  (z4+z2+Lb)
//     out_b[l][b,o,h] = bb[o]+brcz[b,o]     + sum_c bw[o,c]*ccat[b,c,h]
// ccat: col_means[l] | biases[l] | row_means[l+1]
// Threads: B*(1024+1024+512)=5120 -> 20 blocks.
__global__ __launch_bounds__(256) void k5_colz(
    const float* __restrict__ cs0, const float* __restrict__ cs1, const float* __restrict__ cs2,
    const float* __restrict__ rs1, const float* __restrict__ rs2,
    const float* __restrict__ bias0, const float* __restrict__ bias1, const float* __restrict__ bias2,
    const float* __restrict__ cw0, const float* __restrict__ cw1, const float* __restrict__ cw2,
    const float* __restrict__ cb0, const float* __restrict__ cb1, const float* __restrict__ cb2,
    const float* __restrict__ Lb0, const float* __restrict__ Lb1, const float* __restrict__ Lb2,
    const float* __restrict__ bw0, const float* __restrict__ bw1, const float* __restrict__ bw2,
    const float* __restrict__ bb0, const float* __restrict__ bb1, const float* __restrict__ bb2,
    const float* __restrict__ rcz, const float* __restrict__ brcz,
    float* __restrict__ colz0, float* __restrict__ colz1, float* __restrict__ colz2,
    float* __restrict__ outb0, float* __restrict__ outb1, float* __restrict__ outb2) {
  const int gid = blockIdx.x * 256 + threadIdx.x;
  int l, rem;
  if (gid < 2048)      { l = 0; rem = gid; }
  else if (gid < 4096) { l = 1; rem = gid - 2048; }
  else                 { l = 2; rem = gid - 4096; }
  const int lnout = (l == 2) ? 9 : 10;
  const int nout  = 1 << lnout;
  const int nin   = (l == 0) ? 512 : 1024;
  const int b = rem >> lnout;
  const int h = rem & (nout - 1);
  const float* cs   = (l == 0) ? cs0 : (l == 1) ? cs1 : cs2;
  const float* bias = (l == 0) ? bias0 : (l == 1) ? bias1 : bias2;
  float src[48];
  const float inv_nin = 1.f / (float)nin;
  for (int c = 0; c < 16; ++c) {
    src[c]      = cs[(b * 16 + c) * nout + h] * inv_nin;
    src[16 + c] = bias[(b * 16 + c) * nout + h];
  }
  int cin = 32;
  if (l < 2) {
    cin = 48;
    const float* rsn = (l == 0) ? rs1 : rs2;           // row sums of layer l+1 (len nout)
    const float inv_nout_next = (l == 0) ? (1.f / 1024.f) : (1.f / 512.f);
    for (int c = 0; c < 16; ++c)
      src[32 + c] = rsn[(b * 16 + c) * nout + h] * inv_nout_next;
  }
  const float* cw = (l == 0) ? cw0 : (l == 1) ? cw1 : cw2;
  const float* cb = (l == 0) ? cb0 : (l == 1) ? cb1 : cb2;
  const float* Lb = (l == 0) ? Lb0 : (l == 1) ? Lb1 : Lb2;
  const float* bw = (l == 0) ? bw0 : (l == 1) ? bw1 : bw2;
  const float* bb = (l == 0) ? bb0 : (l == 1) ? bb1 : bb2;
  float* colz = (l == 0) ? colz0 : (l == 1) ? colz1 : colz2;
  float* outb = (l == 0) ? outb0 : (l == 1) ? outb1 : outb2;
  for (int o = 0; o < 16; ++o) {
    float s1 = cb[o] + Lb[o] + rcz[(l * 2 + b) * 16 + o];
    float s2 = bb[o] + brcz[(l * 2 + b) * 16 + o];
    for (int c = 0; c < cin; ++c) {
      const float v = src[c];
      s1 += cw[o * cin + c] * v;
      s2 += bw[o * cin + c] * v;
    }
    colz[(b * 16 + o) * nout + h] = s1;
    outb[(b * 16 + o) * nout + h] = s2;
  }
}

// ---------------------------------------------------------------------------
// K6: out_w[b,o,h,wi] = sum_c Lw[o,c]*W[b,c,h,wi] + rowz[b,o,wi] + colz[b,o,h]
// One thread per (b,h,wi4): 16 f4 channel loads, 16x16 channel mix, 16 f4 nt stores.
template <int LOG_NOUT, int LOG_V4>
__global__ __launch_bounds__(256) void k6_main(
    const float* __restrict__ w, const float* __restrict__ rowz,
    const float* __restrict__ colz, const float* __restrict__ Lw,
    float* __restrict__ out) {
  constexpr int V4 = 1 << LOG_V4;
  constexpr int NOUTL = 1 << LOG_NOUT;
  const int tid = blockIdx.x * 256 + threadIdx.x;
  const int wi4 = tid & (V4 - 1);
  const int rem = tid >> LOG_V4;
  const int h = rem & (NOUTL - 1);
  const int b = rem >> LOG_NOUT;
  const f4* __restrict__ wp  = (const f4*)w;
  const f4* __restrict__ rzp = (const f4*)rowz;
  f4* __restrict__ op = (f4*)out;

  f4 wv[16];
  #pragma unroll
  for (int c = 0; c < 16; ++c) {
    const int idx = ((((b << 4) + c) << LOG_NOUT) + h << LOG_V4) + wi4;
    wv[c] = wp[idx];
  }
  #pragma unroll
  for (int o = 0; o < 16; ++o) {
    const int ro = (b << 4) + o;
    f4 a = rzp[(ro << LOG_V4) + wi4];
    a += colz[(ro << LOG_NOUT) + h];            // broadcast add
    #pragma unroll
    for (int c = 0; c < 16; ++c)
      a += Lw[o * 16 + c] * wv[c];              // Lw loads are uniform -> s_load
    const int oidx = ((ro << LOG_NOUT) + h << LOG_V4) + wi4;
    __builtin_nontemporal_store(a, &op[oidx]);  // don't evict W from L3
  }
}

// ---------------------------------------------------------------------------
extern "C" void kernel_launch(void* const* d_in, const int* in_sizes, int n_in,
                              void* d_out, int out_size, void* d_ws, size_t ws_size,
                              hipStream_t stream) {
  const float *w[3], *bias[3];
  const bool interleaved = (in_sizes[1] == 2 * 16 * 1024);  // b0 right after w0
  if (interleaved) {
    w[0] = (const float*)d_in[0]; bias[0] = (const float*)d_in[1];
    w[1] = (const float*)d_in[2]; bias[1] = (const float*)d_in[3];
    w[2] = (const float*)d_in[4]; bias[2] = (const float*)d_in[5];
  } else {
    for (int i = 0; i < 3; ++i) { w[i] = (const float*)d_in[i]; bias[i] = (const float*)d_in[3 + i]; }
  }
  const float *Lw[3], *Lb[3], *rcw[3], *rcb[3], *rw[3], *rb[3], *cw[3], *cb[3], *bw[3], *bb[3], *brcw[3], *brcb[3];
  for (int i = 0; i < 3; ++i) {
    const int base = 6 + 12 * i;
    Lw[i]   = (const float*)d_in[base + 0];  Lb[i]   = (const float*)d_in[base + 1];
    rcw[i]  = (const float*)d_in[base + 2];  rcb[i]  = (const float*)d_in[base + 3];
    rw[i]   = (const float*)d_in[base + 4];  rb[i]   = (const float*)d_in[base + 5];
    cw[i]   = (const float*)d_in[base + 6];  cb[i]   = (const float*)d_in[base + 7];
    bw[i]   = (const float*)d_in[base + 8];  bb[i]   = (const float*)d_in[base + 9];
    brcw[i] = (const float*)d_in[base + 10]; brcb[i] = (const float*)d_in[base + 11];
  }

  float* ws = (float*)d_ws;
  float* rs0 = ws;             // [2,16,512]
  float* rs1 = ws + 16384;     // [2,16,1024]
  float* rs2 = ws + 49152;     // [2,16,1024]
  float* cs0 = ws + 81920;     // [2,16,1024]
  float* cs1 = ws + 114688;    // [2,16,1024]
  float* cs2 = ws + 147456;    // [2,16,512]
  float* b_mean  = ws + 163840;  // [3,2,16]
  float* rc_mean = ws + 163936;
  float* rcz     = ws + 164032;
  float* brcz    = ws + 164128;
  float* rowz0 = ws + 164224;  // [2,16,512]
  float* rowz1 = ws + 180608;  // [2,16,1024]
  float* rowz2 = ws + 213376;  // [2,16,1024]
  float* colz0 = ws + 246144;  // [2,16,1024]
  float* colz1 = ws + 278912;  // [2,16,1024]
  float* colz2 = ws + 311680;  // [2,16,512]

  float* out = (float*)d_out;
  float* outw0 = out;
  float* outw1 = out + 16777216;
  float* outw2 = out + 50331648;
  float* outb0 = out + 67108864;
  float* outb1 = out + 67141632;
  float* outb2 = out + 67174400;

  // zero the atomic row-sum accumulators with our own kernel:
  // rocprof showed the runtime's fillBufferAligned for this 320 KB memset
  // costing 155 us (2 GB/s) inside the timed graph.
  k0_zero<<<80, 256, 0, stream>>>(ws);

  k1_reduce<<<2560, 256, 0, stream>>>(w[0], w[1], w[2], rs0, rs1, rs2, cs0, cs1, cs2);
  k2_means<<<96, 256, 0, stream>>>(bias[0], bias[1], bias[2], cs0, cs1, cs2, b_mean, rc_mean);
  k3_wb<<<1, 256, 0, stream>>>(rcw[0], rcw[1], rcw[2], rcb[0], rcb[1], rcb[2],
                               brcw[0], brcw[1], brcw[2], brcb[0], brcb[1], brcb[2],
                               b_mean, rc_mean, rcz, brcz);
  k4_rowz<<<20, 256, 0, stream>>>(rs0, rs1, rs2, cs0, cs1, bias[0], bias[1],
                                  rw[0], rw[1], rw[2], rb[0], rb[1], rb[2],
                                  rowz0, rowz1, rowz2);
  k5_colz<<<20, 256, 0, stream>>>(cs0, cs1, cs2, rs1, rs2, bias[0], bias[1], bias[2],
                                  cw[0], cw[1], cw[2], cb[0], cb[1], cb[2],
                                  Lb[0], Lb[1], Lb[2], bw[0], bw[1], bw[2],
                                  bb[0], bb[1], bb[2], rcz, brcz,
                                  colz0, colz1, colz2, outb0, outb1, outb2);

  // k1 streamed W in order L0,L1,L2 -> the 256 MiB L3 ends holding W2 and the
  // tail of W1. Run k6 in REVERSE layer order so pass-2 re-reads hit L3.
  k6_main<9, 8><<<1024, 256, 0, stream>>>(w[2], rowz2, colz2, Lw[2], outw2);
  k6_main<10, 8><<<2048, 256, 0, stream>>>(w[1], rowz1, colz1, Lw[1], outw1);
  k6_main<10, 7><<<1024, 256, 0, stream>>>(w[0], rowz0, colz0, Lw[0], outw0);
}

// Round 3
// 303.928 us; speedup vs baseline: 1.2454x; 1.2454x over previous
//
#include <hip/hip_runtime.h>

// NPLinear: 3 layers, B=2, C=CO=16
// NIN  = {512,1024,1024}, NOUT = {1024,1024,512}
// out = [out_w0, out_w1, out_w2, out_b0, out_b1, out_b2] flat fp32

typedef float f4 __attribute__((ext_vector_type(4)));

__device__ __forceinline__ float wave_red64(float s) {
  #pragma unroll
  for (int m = 1; m < 64; m <<= 1) s += __shfl_xor(s, m, 64);
  return s;
}

// ---------------------------------------------------------------------------
// K0: zero the atomic row-sum accumulators. 80 blocks x 256 f4 = 320 KB.
__global__ __launch_bounds__(256) void k0_zero(float* __restrict__ p) {
  f4* p4 = (f4*)p;
  p4[blockIdx.x * 256 + threadIdx.x] = (f4){0.f, 0.f, 0.f, 0.f};
}

// ---------------------------------------------------------------------------
// K1: fused row/col sums of all three W tensors.
// Block = 256 threads, handles 32 rows of one (b,c) slice.
// col_sum (per-row sum over n_in): wave reduce -> LDS -> direct store.
// row_sum (per-col sum over n_out): per-thread f4 accumulator -> atomicAdd.
__global__ __launch_bounds__(256) void k1_reduce(
    const float* __restrict__ w0, const float* __restrict__ w1, const float* __restrict__ w2,
    float* __restrict__ rs0, float* __restrict__ rs1, float* __restrict__ rs2,
    float* __restrict__ cs0, float* __restrict__ cs1, float* __restrict__ cs2) {
  __shared__ float part[32][4];
  const int bid = blockIdx.x, t = threadIdx.x;
  int l, rb;
  if (bid < 1024)      { l = 0; rb = bid; }
  else if (bid < 2048) { l = 1; rb = bid - 1024; }
  else                 { l = 2; rb = bid - 2048; }
  const float* w = (l == 0) ? w0 : (l == 1) ? w1 : w2;
  float* rs = (l == 0) ? rs0 : (l == 1) ? rs1 : rs2;
  float* cs = (l == 0) ? cs0 : (l == 1) ? cs1 : cs2;
  const int nout = (l == 2) ? 512 : 1024;
  const int nin  = (l == 0) ? 512 : 1024;
  const int log_chunks = (l == 2) ? 4 : 5;       // nout/32 chunks per slice
  const int slice = rb >> log_chunks;            // b*16+c in [0,32)
  const int chunk = rb & ((1 << log_chunks) - 1);
  const int v4  = nin >> 2;                      // 128 or 256 float4 per row
  const int c4  = t & (v4 - 1);
  const int ro  = t / v4;                        // 0 (v4=256) or 0/1 (v4=128)
  const int rpi = 256 / v4;                      // rows per iteration
  const int wid = t >> 6, lane = t & 63;

  if (t < 128) part[t >> 2][t & 3] = 0.f;
  __syncthreads();

  const f4* wp = (const f4*)w;
  int base = (slice * nout + chunk * 32 + ro) * v4 + c4;
  f4 cacc = {0.f, 0.f, 0.f, 0.f};
  for (int it = 0; it < 32; it += rpi) {
    f4 v = wp[base];
    base += 256;                                 // rpi * v4 == 256 always
    cacc += v;
    float s = v[0] + v[1] + v[2] + v[3];
    s = wave_red64(s);
    if (lane == 0) part[it + ro][wid] = s;       // waves never straddle rows
  }
  __syncthreads();
  if (t < 32)
    cs[slice * nout + chunk * 32 + t] = part[t][0] + part[t][1] + part[t][2] + part[t][3];

  float* rsb = rs + slice * nin + c4 * 4;
  unsafeAtomicAdd(rsb + 0, cacc[0]);
  unsafeAtomicAdd(rsb + 1, cacc[1]);
  unsafeAtomicAdd(rsb + 2, cacc[2]);
  unsafeAtomicAdd(rsb + 3, cacc[3]);
}

// ---------------------------------------------------------------------------
// K2: bias means + rc means. 96 blocks, one per (i,b,c).
__global__ __launch_bounds__(256) void k2_means(
    const float* __restrict__ b0, const float* __restrict__ b1, const float* __restrict__ b2,
    const float* __restrict__ cs0, const float* __restrict__ cs1, const float* __restrict__ cs2,
    float* __restrict__ b_mean, float* __restrict__ rc_mean) {
  const int bid = blockIdx.x, t = threadIdx.x;
  const int i = bid >> 5, b = (bid >> 4) & 1, c = bid & 15;
  const int nout = (i == 2) ? 512 : 1024;
  const int nin  = (i == 0) ? 512 : 1024;
  const float* bias = (i == 0) ? b0 : (i == 1) ? b1 : b2;
  const float* cs   = (i == 0) ? cs0 : (i == 1) ? cs1 : cs2;
  const int rowoff = (b * 16 + c) * nout;
  float s1 = 0.f, s2 = 0.f;
  for (int j = t; j < nout; j += 256) { s1 += bias[rowoff + j]; s2 += cs[rowoff + j]; }
  s1 = wave_red64(s1);
  s2 = wave_red64(s2);
  __shared__ float p1[4], p2[4];
  if ((t & 63) == 0) { p1[t >> 6] = s1; p2[t >> 6] = s2; }
  __syncthreads();
  if (t == 0) {
    float t1 = p1[0] + p1[1] + p1[2] + p1[3];
    float t2 = p2[0] + p2[1] + p2[2] + p2[3];
    b_mean[(i * 2 + b) * 16 + c]  = t1 / (float)nout;
    rc_mean[(i * 2 + b) * 16 + c] = t2 / ((float)nout * (float)nin);
  }
}

// ---------------------------------------------------------------------------
// K3: wb = [rc_means | b_means], then rcz/brcz tiny GEMMs. Single block.
__global__ __launch_bounds__(256) void k3_wb(
    const float* __restrict__ rcw0, const float* __restrict__ rcw1, const float* __restrict__ rcw2,
    const float* __restrict__ rcb0, const float* __restrict__ rcb1, const float* __restrict__ rcb2,
    const float* __restrict__ brcw0, const float* __restrict__ brcw1, const float* __restrict__ brcw2,
    const float* __restrict__ brcb0, const float* __restrict__ brcb1, const float* __restrict__ brcb2,
    const float* __restrict__ b_mean, const float* __restrict__ rc_mean,
    float* __restrict__ rcz, float* __restrict__ brcz) {
  __shared__ float wbs[192];
  const int t = threadIdx.x;
  if (t < 192) {
    int b = t / 96, jj = t % 96;
    float v;
    if (jj < 48) v = rc_mean[((jj >> 4) * 2 + b) * 16 + (jj & 15)];
    else { int j2 = jj - 48; v = b_mean[((j2 >> 4) * 2 + b) * 16 + (j2 & 15)]; }
    wbs[t] = v;
  }
  __syncthreads();
  if (t < 96) {
    const int i = t >> 5, b = (t >> 4) & 1, o = t & 15;
    const float* rcw  = (i == 0) ? rcw0  : (i == 1) ? rcw1  : rcw2;
    const float* rcb  = (i == 0) ? rcb0  : (i == 1) ? rcb1  : rcb2;
    const float* brcw = (i == 0) ? brcw0 : (i == 1) ? brcw1 : brcw2;
    const float* brcb = (i == 0) ? brcb0 : (i == 1) ? brcb1 : brcb2;
    float s1 = rcb[o], s2 = brcb[o];
    const float* wbp = wbs + b * 96;
    for (int j = 0; j < 96; ++j) {
      s1 += wbp[j] * rcw[o * 96 + j];
      s2 += wbp[j] * brcw[o * 96 + j];
    }
    rcz[(i * 2 + b) * 16 + o]  = s1;
    brcz[(i * 2 + b) * 16 + o] = s2;
  }
}

// ---------------------------------------------------------------------------
// K45: fused k4 (rowz, blocks 0..19) + k5 (colz/out_b, blocks 20..39).
__global__ __launch_bounds__(256) void k45_rowcol(
    const float* __restrict__ rs0, const float* __restrict__ rs1, const float* __restrict__ rs2,
    const float* __restrict__ cs0, const float* __restrict__ cs1, const float* __restrict__ cs2,
    const float* __restrict__ bias0, const float* __restrict__ bias1, const float* __restrict__ bias2,
    const float* __restrict__ rw0, const float* __restrict__ rw1, const float* __restrict__ rw2,
    const float* __restrict__ rb0, const float* __restrict__ rb1, const float* __restrict__ rb2,
    const float* __restrict__ cw0, const float* __restrict__ cw1, const float* __restrict__ cw2,
    const float* __restrict__ cb0, const float* __restrict__ cb1, const float* __restrict__ cb2,
    const float* __restrict__ Lb0, const float* __restrict__ Lb1, const float* __restrict__ Lb2,
    const float* __restrict__ bw0, const float* __restrict__ bw1, const float* __restrict__ bw2,
    const float* __restrict__ bb0, const float* __restrict__ bb1, const float* __restrict__ bb2,
    const float* __restrict__ rcz, const float* __restrict__ brcz,
    float* __restrict__ rowz0, float* __restrict__ rowz1, float* __restrict__ rowz2,
    float* __restrict__ colz0, float* __restrict__ colz1, float* __restrict__ colz2,
    float* __restrict__ outb0, float* __restrict__ outb1, float* __restrict__ outb2) {
  if (blockIdx.x < 20) {
    // ---- k4: rowz[l][b,o,wi] = rb[o] + sum_c rw[o,c]*rcat[b,c,wi]
    const int gid = blockIdx.x * 256 + threadIdx.x;
    int l, rem;
    if (gid < 1024)      { l = 0; rem = gid; }
    else if (gid < 3072) { l = 1; rem = gid - 1024; }
    else                 { l = 2; rem = gid - 3072; }
    const int lnin = (l == 0) ? 9 : 10;
    const int nin  = 1 << lnin;
    const int nout = (l == 2) ? 512 : 1024;
    const int b  = rem >> lnin;
    const int wi = rem & (nin - 1);
    const float* rs = (l == 0) ? rs0 : (l == 1) ? rs1 : rs2;
    float src[48];
    const float inv_nout = 1.f / (float)nout;
    for (int c = 0; c < 16; ++c) src[c] = rs[(b * 16 + c) * nin + wi] * inv_nout;
    int rin = 16;
    if (l > 0) {
      rin = 48;
      const float* csm = (l == 1) ? cs0 : cs1;
      const float* bm  = (l == 1) ? bias0 : bias1;
      const float inv_nin_prev = (l == 1) ? (1.f / 512.f) : (1.f / 1024.f);
      for (int c = 0; c < 16; ++c) {
        src[16 + c] = csm[(b * 16 + c) * nin + wi] * inv_nin_prev;
        src[32 + c] = bm[(b * 16 + c) * nin + wi];
      }
    }
    const float* rw = (l == 0) ? rw0 : (l == 1) ? rw1 : rw2;
    const float* rb = (l == 0) ? rb0 : (l == 1) ? rb1 : rb2;
    float* rowz = (l == 0) ? rowz0 : (l == 1) ? rowz1 : rowz2;
    for (int o = 0; o < 16; ++o) {
      float s = rb[o];
      for (int c = 0; c < rin; ++c) s += rw[o * rin + c] * src[c];
      rowz[(b * 16 + o) * nin + wi] = s;
    }
  } else {
    // ---- k5: colz + out_b
    const int gid = (blockIdx.x - 20) * 256 + threadIdx.x;
    int l, rem;
    if (gid < 2048)      { l = 0; rem = gid; }
    else if (gid < 4096) { l = 1; rem = gid - 2048; }
    else                 { l = 2; rem = gid - 4096; }
    const int lnout = (l == 2) ? 9 : 10;
    const int nout  = 1 << lnout;
    const int nin   = (l == 0) ? 512 : 1024;
    const int b = rem >> lnout;
    const int h = rem & (nout - 1);
    const float* cs   = (l == 0) ? cs0 : (l == 1) ? cs1 : cs2;
    const float* bias = (l == 0) ? bias0 : (l == 1) ? bias1 : bias2;
    float src[48];
    const float inv_nin = 1.f / (float)nin;
    for (int c = 0; c < 16; ++c) {
      src[c]      = cs[(b * 16 + c) * nout + h] * inv_nin;
      src[16 + c] = bias[(b * 16 + c) * nout + h];
    }
    int cin = 32;
    if (l < 2) {
      cin = 48;
      const float* rsn = (l == 0) ? rs1 : rs2;
      const float inv_nout_next = (l == 0) ? (1.f / 1024.f) : (1.f / 512.f);
      for (int c = 0; c < 16; ++c)
        src[32 + c] = rsn[(b * 16 + c) * nout + h] * inv_nout_next;
    }
    const float* cw = (l == 0) ? cw0 : (l == 1) ? cw1 : cw2;
    const float* cb = (l == 0) ? cb0 : (l == 1) ? cb1 : cb2;
    const float* Lb = (l == 0) ? Lb0 : (l == 1) ? Lb1 : Lb2;
    const float* bw = (l == 0) ? bw0 : (l == 1) ? bw1 : bw2;
    const float* bb = (l == 0) ? bb0 : (l == 1) ? bb1 : bb2;
    float* colz = (l == 0) ? colz0 : (l == 1) ? colz1 : colz2;
    float* outb = (l == 0) ? outb0 : (l == 1) ? outb1 : outb2;
    for (int o = 0; o < 16; ++o) {
      float s1 = cb[o] + Lb[o] + rcz[(l * 2 + b) * 16 + o];
      float s2 = bb[o] + brcz[(l * 2 + b) * 16 + o];
      for (int c = 0; c < cin; ++c) {
        const float v = src[c];
        s1 += cw[o * cin + c] * v;
        s2 += bw[o * cin + c] * v;
      }
      colz[(b * 16 + o) * nout + h] = s1;
      outb[(b * 16 + o) * nout + h] = s2;
    }
  }
}

// ---------------------------------------------------------------------------
// K6: out_w[b,o,h,wi] = sum_c Lw[o,c]*W[b,c,h,wi] + rowz[b,o,wi] + colz[b,o,h]
// Plain (cached) stores this round — isolating the nontemporal-store effect.
// colz hoisted out of the o-loop into registers.
template <int LOG_NOUT, int LOG_V4>
__global__ __launch_bounds__(256) void k6_main(
    const float* __restrict__ w, const float* __restrict__ rowz,
    const float* __restrict__ colz, const float* __restrict__ Lw,
    float* __restrict__ out) {
  constexpr int V4 = 1 << LOG_V4;
  constexpr int NOUTL = 1 << LOG_NOUT;
  const int tid = blockIdx.x * 256 + threadIdx.x;
  const int wi4 = tid & (V4 - 1);
  const int rem = tid >> LOG_V4;
  const int h = rem & (NOUTL - 1);
  const int b = rem >> LOG_NOUT;
  const f4* __restrict__ wp  = (const f4*)w;
  const f4* __restrict__ rzp = (const f4*)rowz;
  f4* __restrict__ op = (f4*)out;

  float cz[16];
  #pragma unroll
  for (int o = 0; o < 16; ++o)
    cz[o] = colz[((((b << 4) + o) << LOG_NOUT)) + h];

  f4 wv[16];
  #pragma unroll
  for (int c = 0; c < 16; ++c) {
    const int idx = ((((b << 4) + c) << LOG_NOUT) + h) * V4 + wi4;
    wv[c] = wp[idx];
  }
  #pragma unroll
  for (int o = 0; o < 16; ++o) {
    const int ro = (b << 4) + o;
    f4 a = rzp[(ro << LOG_V4) + wi4];
    a += cz[o];
    #pragma unroll
    for (int c = 0; c < 16; ++c)
      a += Lw[o * 16 + c] * wv[c];              // Lw loads are uniform -> s_load
    op[((ro << LOG_NOUT) + h) * V4 + wi4] = a;  // plain store (was nontemporal)
  }
}

// ---------------------------------------------------------------------------
extern "C" void kernel_launch(void* const* d_in, const int* in_sizes, int n_in,
                              void* d_out, int out_size, void* d_ws, size_t ws_size,
                              hipStream_t stream) {
  const float *w[3], *bias[3];
  const bool interleaved = (in_sizes[1] == 2 * 16 * 1024);  // b0 right after w0
  if (interleaved) {
    w[0] = (const float*)d_in[0]; bias[0] = (const float*)d_in[1];
    w[1] = (const float*)d_in[2]; bias[1] = (const float*)d_in[3];
    w[2] = (const float*)d_in[4]; bias[2] = (const float*)d_in[5];
  } else {
    for (int i = 0; i < 3; ++i) { w[i] = (const float*)d_in[i]; bias[i] = (const float*)d_in[3 + i]; }
  }
  const float *Lw[3], *Lb[3], *rcw[3], *rcb[3], *rw[3], *rb[3], *cw[3], *cb[3], *bw[3], *bb[3], *brcw[3], *brcb[3];
  for (int i = 0; i < 3; ++i) {
    const int base = 6 + 12 * i;
    Lw[i]   = (const float*)d_in[base + 0];  Lb[i]   = (const float*)d_in[base + 1];
    rcw[i]  = (const float*)d_in[base + 2];  rcb[i]  = (const float*)d_in[base + 3];
    rw[i]   = (const float*)d_in[base + 4];  rb[i]   = (const float*)d_in[base + 5];
    cw[i]   = (const float*)d_in[base + 6];  cb[i]   = (const float*)d_in[base + 7];
    bw[i]   = (const float*)d_in[base + 8];  bb[i]   = (const float*)d_in[base + 9];
    brcw[i] = (const float*)d_in[base + 10]; brcb[i] = (const float*)d_in[base + 11];
  }

  float* ws = (float*)d_ws;
  float* rs0 = ws;             // [2,16,512]
  float* rs1 = ws + 16384;     // [2,16,1024]
  float* rs2 = ws + 49152;     // [2,16,1024]
  float* cs0 = ws + 81920;     // [2,16,1024]
  float* cs1 = ws + 114688;    // [2,16,1024]
  float* cs2 = ws + 147456;    // [2,16,512]
  float* b_mean  = ws + 163840;  // [3,2,16]
  float* rc_mean = ws + 163936;
  float* rcz     = ws + 164032;
  float* brcz    = ws + 164128;
  float* rowz0 = ws + 164224;  // [2,16,512]
  float* rowz1 = ws + 180608;  // [2,16,1024]
  float* rowz2 = ws + 213376;  // [2,16,1024]
  float* colz0 = ws + 246144;  // [2,16,1024]
  float* colz1 = ws + 278912;  // [2,16,1024]
  float* colz2 = ws + 311680;  // [2,16,512]

  float* out = (float*)d_out;
  float* outw0 = out;
  float* outw1 = out + 16777216;
  float* outw2 = out + 50331648;
  float* outb0 = out + 67108864;
  float* outb1 = out + 67141632;
  float* outb2 = out + 67174400;

  k0_zero<<<80, 256, 0, stream>>>(ws);
  k1_reduce<<<2560, 256, 0, stream>>>(w[0], w[1], w[2], rs0, rs1, rs2, cs0, cs1, cs2);
  k2_means<<<96, 256, 0, stream>>>(bias[0], bias[1], bias[2], cs0, cs1, cs2, b_mean, rc_mean);
  k3_wb<<<1, 256, 0, stream>>>(rcw[0], rcw[1], rcw[2], rcb[0], rcb[1], rcb[2],
                               brcw[0], brcw[1], brcw[2], brcb[0], brcb[1], brcb[2],
                               b_mean, rc_mean, rcz, brcz);
  k45_rowcol<<<40, 256, 0, stream>>>(rs0, rs1, rs2, cs0, cs1, cs2,
                                     bias[0], bias[1], bias[2],
                                     rw[0], rw[1], rw[2], rb[0], rb[1], rb[2],
                                     cw[0], cw[1], cw[2], cb[0], cb[1], cb[2],
                                     Lb[0], Lb[1], Lb[2], bw[0], bw[1], bw[2],
                                     bb[0], bb[1], bb[2], rcz, brcz,
                                     rowz0, rowz1, rowz2, colz0, colz1, colz2,
                                     outb0, outb1, outb2);

  // reverse layer order: k1 streamed L0,L1,L2 so L3 likely holds W2 + tail of W1
  k6_main<9, 8><<<1024, 256, 0, stream>>>(w[2], rowz2, colz2, Lw[2], outw2);
  k6_main<10, 8><<<2048, 256, 0, stream>>>(w[1], rowz1, colz1, Lw[1], outw1);
  k6_main<10, 7><<<1024, 256, 0, stream>>>(w[0], rowz0, colz0, Lw[0], outw0);
}

// Round 4
// 297.692 us; speedup vs baseline: 1.2715x; 1.0209x over previous
//
#include <hip/hip_runtime.h>

// NPLinear: 3 layers, B=2, C=CO=16
// NIN  = {512,1024,1024}, NOUT = {1024,1024,512}
// out = [out_w0, out_w1, out_w2, out_b0, out_b1, out_b2] flat fp32

typedef float f4 __attribute__((ext_vector_type(4)));

__device__ __forceinline__ float wave_red64(float s) {
  #pragma unroll
  for (int m = 1; m < 64; m <<= 1) s += __shfl_xor(s, m, 64);
  return s;
}

// ---------------------------------------------------------------------------
// K0: zero the atomic row-sum accumulators. 80 blocks x 256 f4 = 320 KB.
__global__ __launch_bounds__(256) void k0_zero(float* __restrict__ p) {
  f4* p4 = (f4*)p;
  p4[blockIdx.x * 256 + threadIdx.x] = (f4){0.f, 0.f, 0.f, 0.f};
}

// ---------------------------------------------------------------------------
// K1: fused row/col sums of all three W tensors.
__global__ __launch_bounds__(256) void k1_reduce(
    const float* __restrict__ w0, const float* __restrict__ w1, const float* __restrict__ w2,
    float* __restrict__ rs0, float* __restrict__ rs1, float* __restrict__ rs2,
    float* __restrict__ cs0, float* __restrict__ cs1, float* __restrict__ cs2) {
  __shared__ float part[32][4];
  const int bid = blockIdx.x, t = threadIdx.x;
  int l, rb;
  if (bid < 1024)      { l = 0; rb = bid; }
  else if (bid < 2048) { l = 1; rb = bid - 1024; }
  else                 { l = 2; rb = bid - 2048; }
  const float* w = (l == 0) ? w0 : (l == 1) ? w1 : w2;
  float* rs = (l == 0) ? rs0 : (l == 1) ? rs1 : rs2;
  float* cs = (l == 0) ? cs0 : (l == 1) ? cs1 : cs2;
  const int nout = (l == 2) ? 512 : 1024;
  const int nin  = (l == 0) ? 512 : 1024;
  const int log_chunks = (l == 2) ? 4 : 5;       // nout/32 chunks per slice
  const int slice = rb >> log_chunks;            // b*16+c in [0,32)
  const int chunk = rb & ((1 << log_chunks) - 1);
  const int v4  = nin >> 2;                      // 128 or 256 float4 per row
  const int c4  = t & (v4 - 1);
  const int ro  = t / v4;                        // 0 (v4=256) or 0/1 (v4=128)
  const int rpi = 256 / v4;                      // rows per iteration
  const int wid = t >> 6, lane = t & 63;

  if (t < 128) part[t >> 2][t & 3] = 0.f;
  __syncthreads();

  const f4* wp = (const f4*)w;
  int base = (slice * nout + chunk * 32 + ro) * v4 + c4;
  f4 cacc = {0.f, 0.f, 0.f, 0.f};
  for (int it = 0; it < 32; it += rpi) {
    f4 v = wp[base];
    base += 256;                                 // rpi * v4 == 256 always
    cacc += v;
    float s = v[0] + v[1] + v[2] + v[3];
    s = wave_red64(s);
    if (lane == 0) part[it + ro][wid] = s;       // waves never straddle rows
  }
  __syncthreads();
  if (t < 32)
    cs[slice * nout + chunk * 32 + t] = part[t][0] + part[t][1] + part[t][2] + part[t][3];

  float* rsb = rs + slice * nin + c4 * 4;
  unsafeAtomicAdd(rsb + 0, cacc[0]);
  unsafeAtomicAdd(rsb + 1, cacc[1]);
  unsafeAtomicAdd(rsb + 2, cacc[2]);
  unsafeAtomicAdd(rsb + 3, cacc[3]);
}

// ---------------------------------------------------------------------------
// K2: bias means + rc means. 96 blocks, one per (i,b,c).
__global__ __launch_bounds__(256) void k2_means(
    const float* __restrict__ b0, const float* __restrict__ b1, const float* __restrict__ b2,
    const float* __restrict__ cs0, const float* __restrict__ cs1, const float* __restrict__ cs2,
    float* __restrict__ b_mean, float* __restrict__ rc_mean) {
  const int bid = blockIdx.x, t = threadIdx.x;
  const int i = bid >> 5, b = (bid >> 4) & 1, c = bid & 15;
  const int nout = (i == 2) ? 512 : 1024;
  const int nin  = (i == 0) ? 512 : 1024;
  const float* bias = (i == 0) ? b0 : (i == 1) ? b1 : b2;
  const float* cs   = (i == 0) ? cs0 : (i == 1) ? cs1 : cs2;
  const int rowoff = (b * 16 + c) * nout;
  float s1 = 0.f, s2 = 0.f;
  for (int j = t; j < nout; j += 256) { s1 += bias[rowoff + j]; s2 += cs[rowoff + j]; }
  s1 = wave_red64(s1);
  s2 = wave_red64(s2);
  __shared__ float p1[4], p2[4];
  if ((t & 63) == 0) { p1[t >> 6] = s1; p2[t >> 6] = s2; }
  __syncthreads();
  if (t == 0) {
    float t1 = p1[0] + p1[1] + p1[2] + p1[3];
    float t2 = p2[0] + p2[1] + p2[2] + p2[3];
    b_mean[(i * 2 + b) * 16 + c]  = t1 / (float)nout;
    rc_mean[(i * 2 + b) * 16 + c] = t2 / ((float)nout * (float)nin);
  }
}

// ---------------------------------------------------------------------------
// K3: wb = [rc_means | b_means], then rcz/brcz tiny GEMMs. Single block.
__global__ __launch_bounds__(256) void k3_wb(
    const float* __restrict__ rcw0, const float* __restrict__ rcw1, const float* __restrict__ rcw2,
    const float* __restrict__ rcb0, const float* __restrict__ rcb1, const float* __restrict__ rcb2,
    const float* __restrict__ brcw0, const float* __restrict__ brcw1, const float* __restrict__ brcw2,
    const float* __restrict__ brcb0, const float* __restrict__ brcb1, const float* __restrict__ brcb2,
    const float* __restrict__ b_mean, const float* __restrict__ rc_mean,
    float* __restrict__ rcz, float* __restrict__ brcz) {
  __shared__ float wbs[192];
  const int t = threadIdx.x;
  if (t < 192) {
    int b = t / 96, jj = t % 96;
    float v;
    if (jj < 48) v = rc_mean[((jj >> 4) * 2 + b) * 16 + (jj & 15)];
    else { int j2 = jj - 48; v = b_mean[((j2 >> 4) * 2 + b) * 16 + (j2 & 15)]; }
    wbs[t] = v;
  }
  __syncthreads();
  if (t < 96) {
    const int i = t >> 5, b = (t >> 4) & 1, o = t & 15;
    const float* rcw  = (i == 0) ? rcw0  : (i == 1) ? rcw1  : rcw2;
    const float* rcb  = (i == 0) ? rcb0  : (i == 1) ? rcb1  : rcb2;
    const float* brcw = (i == 0) ? brcw0 : (i == 1) ? brcw1 : brcw2;
    const float* brcb = (i == 0) ? brcb0 : (i == 1) ? brcb1 : brcb2;
    float s1 = rcb[o], s2 = brcb[o];
    const float* wbp = wbs + b * 96;
    for (int j = 0; j < 96; ++j) {
      s1 += wbp[j] * rcw[o * 96 + j];
      s2 += wbp[j] * brcw[o * 96 + j];
    }
    rcz[(i * 2 + b) * 16 + o]  = s1;
    brcz[(i * 2 + b) * 16 + o] = s2;
  }
}

// ---------------------------------------------------------------------------
// K45: fused k4 (rowz, blocks 0..19) + k5 (colz/out_b, blocks 20..39).
__global__ __launch_bounds__(256) void k45_rowcol(
    const float* __restrict__ rs0, const float* __restrict__ rs1, const float* __restrict__ rs2,
    const float* __restrict__ cs0, const float* __restrict__ cs1, const float* __restrict__ cs2,
    const float* __restrict__ bias0, const float* __restrict__ bias1, const float* __restrict__ bias2,
    const float* __restrict__ rw0, const float* __restrict__ rw1, const float* __restrict__ rw2,
    const float* __restrict__ rb0, const float* __restrict__ rb1, const float* __restrict__ rb2,
    const float* __restrict__ cw0, const float* __restrict__ cw1, const float* __restrict__ cw2,
    const float* __restrict__ cb0, const float* __restrict__ cb1, const float* __restrict__ cb2,
    const float* __restrict__ Lb0, const float* __restrict__ Lb1, const float* __restrict__ Lb2,
    const float* __restrict__ bw0, const float* __restrict__ bw1, const float* __restrict__ bw2,
    const float* __restrict__ bb0, const float* __restrict__ bb1, const float* __restrict__ bb2,
    const float* __restrict__ rcz, const float* __restrict__ brcz,
    float* __restrict__ rowz0, float* __restrict__ rowz1, float* __restrict__ rowz2,
    float* __restrict__ colz0, float* __restrict__ colz1, float* __restrict__ colz2,
    float* __restrict__ outb0, float* __restrict__ outb1, float* __restrict__ outb2) {
  if (blockIdx.x < 20) {
    const int gid = blockIdx.x * 256 + threadIdx.x;
    int l, rem;
    if (gid < 1024)      { l = 0; rem = gid; }
    else if (gid < 3072) { l = 1; rem = gid - 1024; }
    else                 { l = 2; rem = gid - 3072; }
    const int lnin = (l == 0) ? 9 : 10;
    const int nin  = 1 << lnin;
    const int nout = (l == 2) ? 512 : 1024;
    const int b  = rem >> lnin;
    const int wi = rem & (nin - 1);
    const float* rs = (l == 0) ? rs0 : (l == 1) ? rs1 : rs2;
    float src[48];
    const float inv_nout = 1.f / (float)nout;
    for (int c = 0; c < 16; ++c) src[c] = rs[(b * 16 + c) * nin + wi] * inv_nout;
    int rin = 16;
    if (l > 0) {
      rin = 48;
      const float* csm = (l == 1) ? cs0 : cs1;
      const float* bm  = (l == 1) ? bias0 : bias1;
      const float inv_nin_prev = (l == 1) ? (1.f / 512.f) : (1.f / 1024.f);
      for (int c = 0; c < 16; ++c) {
        src[16 + c] = csm[(b * 16 + c) * nin + wi] * inv_nin_prev;
        src[32 + c] = bm[(b * 16 + c) * nin + wi];
      }
    }
    const float* rw = (l == 0) ? rw0 : (l == 1) ? rw1 : rw2;
    const float* rb = (l == 0) ? rb0 : (l == 1) ? rb1 : rb2;
    float* rowz = (l == 0) ? rowz0 : (l == 1) ? rowz1 : rowz2;
    for (int o = 0; o < 16; ++o) {
      float s = rb[o];
      for (int c = 0; c < rin; ++c) s += rw[o * rin + c] * src[c];
      rowz[(b * 16 + o) * nin + wi] = s;
    }
  } else {
    const int gid = (blockIdx.x - 20) * 256 + threadIdx.x;
    int l, rem;
    if (gid < 2048)      { l = 0; rem = gid; }
    else if (gid < 4096) { l = 1; rem = gid - 2048; }
    else                 { l = 2; rem = gid - 4096; }
    const int lnout = (l == 2) ? 9 : 10;
    const int nout  = 1 << lnout;
    const int nin   = (l == 0) ? 512 : 1024;
    const int b = rem >> lnout;
    const int h = rem & (nout - 1);
    const float* cs   = (l == 0) ? cs0 : (l == 1) ? cs1 : cs2;
    const float* bias = (l == 0) ? bias0 : (l == 1) ? bias1 : bias2;
    float src[48];
    const float inv_nin = 1.f / (float)nin;
    for (int c = 0; c < 16; ++c) {
      src[c]      = cs[(b * 16 + c) * nout + h] * inv_nin;
      src[16 + c] = bias[(b * 16 + c) * nout + h];
    }
    int cin = 32;
    if (l < 2) {
      cin = 48;
      const float* rsn = (l == 0) ? rs1 : rs2;
      const float inv_nout_next = (l == 0) ? (1.f / 1024.f) : (1.f / 512.f);
      for (int c = 0; c < 16; ++c)
        src[32 + c] = rsn[(b * 16 + c) * nout + h] * inv_nout_next;
    }
    const float* cw = (l == 0) ? cw0 : (l == 1) ? cw1 : cw2;
    const float* cb = (l == 0) ? cb0 : (l == 1) ? cb1 : cb2;
    const float* Lb = (l == 0) ? Lb0 : (l == 1) ? Lb1 : Lb2;
    const float* bw = (l == 0) ? bw0 : (l == 1) ? bw1 : bw2;
    const float* bb = (l == 0) ? bb0 : (l == 1) ? bb1 : bb2;
    float* colz = (l == 0) ? colz0 : (l == 1) ? colz1 : colz2;
    float* outb = (l == 0) ? outb0 : (l == 1) ? outb1 : outb2;
    for (int o = 0; o < 16; ++o) {
      float s1 = cb[o] + Lb[o] + rcz[(l * 2 + b) * 16 + o];
      float s2 = bb[o] + brcz[(l * 2 + b) * 16 + o];
      for (int c = 0; c < cin; ++c) {
        const float v = src[c];
        s1 += cw[o * cin + c] * v;
        s2 += bw[o * cin + c] * v;
      }
      colz[(b * 16 + o) * nout + h] = s1;
      outb[(b * 16 + o) * nout + h] = s2;
    }
  }
}

// ---------------------------------------------------------------------------
// K6: out_w[b,o,h,wi] = sum_c Lw[o,c]*W[b,c,h,wi] + rowz[b,o,wi] + colz[b,o,h]
// ALL THREE LAYERS in one launch (diagnostic: a single big dispatch must show
// in the rocprof top-5 if k6 is really the time sink). L2 first (L3-warm).
template <int LOG_NOUT, int LOG_V4>
__device__ __forceinline__ void k6_body(
    const int tid, const float* __restrict__ w, const float* __restrict__ rowz,
    const float* __restrict__ colz, const float* __restrict__ Lw,
    float* __restrict__ out) {
  constexpr int V4 = 1 << LOG_V4;
  constexpr int NOUTL = 1 << LOG_NOUT;
  const int wi4 = tid & (V4 - 1);
  const int rem = tid >> LOG_V4;
  const int h = rem & (NOUTL - 1);
  const int b = rem >> LOG_NOUT;
  const f4* __restrict__ wp  = (const f4*)w;
  const f4* __restrict__ rzp = (const f4*)rowz;
  f4* __restrict__ op = (f4*)out;

  float cz[16];
  #pragma unroll
  for (int o = 0; o < 16; ++o)
    cz[o] = colz[((((b << 4) + o) << LOG_NOUT)) + h];

  f4 wv[16];
  #pragma unroll
  for (int c = 0; c < 16; ++c) {
    const int idx = ((((b << 4) + c) << LOG_NOUT) + h) * V4 + wi4;
    wv[c] = wp[idx];
  }
  #pragma unroll
  for (int o = 0; o < 16; ++o) {
    const int ro = (b << 4) + o;
    f4 a = rzp[(ro << LOG_V4) + wi4];
    a += cz[o];
    #pragma unroll
    for (int c = 0; c < 16; ++c)
      a += Lw[o * 16 + c] * wv[c];              // Lw loads are uniform -> s_load
    op[((ro << LOG_NOUT) + h) * V4 + wi4] = a;
  }
}

__global__ __launch_bounds__(256) void k6_all(
    const float* __restrict__ w0, const float* __restrict__ w1, const float* __restrict__ w2,
    const float* __restrict__ rowz0, const float* __restrict__ rowz1, const float* __restrict__ rowz2,
    const float* __restrict__ colz0, const float* __restrict__ colz1, const float* __restrict__ colz2,
    const float* __restrict__ Lw0, const float* __restrict__ Lw1, const float* __restrict__ Lw2,
    float* __restrict__ outw0, float* __restrict__ outw1, float* __restrict__ outw2) {
  const int bid = blockIdx.x;
  if (bid < 1024) {
    k6_body<9, 8>(bid * 256 + threadIdx.x, w2, rowz2, colz2, Lw2, outw2);
  } else if (bid < 3072) {
    k6_body<10, 8>((bid - 1024) * 256 + threadIdx.x, w1, rowz1, colz1, Lw1, outw1);
  } else {
    k6_body<10, 7>((bid - 3072) * 256 + threadIdx.x, w0, rowz0, colz0, Lw0, outw0);
  }
}

// ---------------------------------------------------------------------------
extern "C" void kernel_launch(void* const* d_in, const int* in_sizes, int n_in,
                              void* d_out, int out_size, void* d_ws, size_t ws_size,
                              hipStream_t stream) {
  const float *w[3], *bias[3];
  const bool interleaved = (in_sizes[1] == 2 * 16 * 1024);  // b0 right after w0
  if (interleaved) {
    w[0] = (const float*)d_in[0]; bias[0] = (const float*)d_in[1];
    w[1] = (const float*)d_in[2]; bias[1] = (const float*)d_in[3];
    w[2] = (const float*)d_in[4]; bias[2] = (const float*)d_in[5];
  } else {
    for (int i = 0; i < 3; ++i) { w[i] = (const float*)d_in[i]; bias[i] = (const float*)d_in[3 + i]; }
  }
  const float *Lw[3], *Lb[3], *rcw[3], *rcb[3], *rw[3], *rb[3], *cw[3], *cb[3], *bw[3], *bb[3], *brcw[3], *brcb[3];
  for (int i = 0; i < 3; ++i) {
    const int base = 6 + 12 * i;
    Lw[i]   = (const float*)d_in[base + 0];  Lb[i]   = (const float*)d_in[base + 1];
    rcw[i]  = (const float*)d_in[base + 2];  rcb[i]  = (const float*)d_in[base + 3];
    rw[i]   = (const float*)d_in[base + 4];  rb[i]   = (const float*)d_in[base + 5];
    cw[i]   = (const float*)d_in[base + 6];  cb[i]   = (const float*)d_in[base + 7];
    bw[i]   = (const float*)d_in[base + 8];  bb[i]   = (const float*)d_in[base + 9];
    brcw[i] = (const float*)d_in[base + 10]; brcb[i] = (const float*)d_in[base + 11];
  }

  float* ws = (float*)d_ws;
  float* rs0 = ws;             // [2,16,512]
  float* rs1 = ws + 16384;     // [2,16,1024]
  float* rs2 = ws + 49152;     // [2,16,1024]
  float* cs0 = ws + 81920;     // [2,16,1024]
  float* cs1 = ws + 114688;    // [2,16,1024]
  float* cs2 = ws + 147456;    // [2,16,512]
  float* b_mean  = ws + 163840;  // [3,2,16]
  float* rc_mean = ws + 163936;
  float* rcz     = ws + 164032;
  float* brcz    = ws + 164128;
  float* rowz0 = ws + 164224;  // [2,16,512]
  float* rowz1 = ws + 180608;  // [2,16,1024]
  float* rowz2 = ws + 213376;  // [2,16,1024]
  float* colz0 = ws + 246144;  // [2,16,1024]
  float* colz1 = ws + 278912;  // [2,16,1024]
  float* colz2 = ws + 311680;  // [2,16,512]

  float* out = (float*)d_out;
  float* outw0 = out;
  float* outw1 = out + 16777216;
  float* outw2 = out + 50331648;
  float* outb0 = out + 67108864;
  float* outb1 = out + 67141632;
  float* outb2 = out + 67174400;

  k0_zero<<<80, 256, 0, stream>>>(ws);
  k1_reduce<<<2560, 256, 0, stream>>>(w[0], w[1], w[2], rs0, rs1, rs2, cs0, cs1, cs2);
  k2_means<<<96, 256, 0, stream>>>(bias[0], bias[1], bias[2], cs0, cs1, cs2, b_mean, rc_mean);
  k3_wb<<<1, 256, 0, stream>>>(rcw[0], rcw[1], rcw[2], rcb[0], rcb[1], rcb[2],
                               brcw[0], brcw[1], brcw[2], brcb[0], brcb[1], brcb[2],
                               b_mean, rc_mean, rcz, brcz);
  k45_rowcol<<<40, 256, 0, stream>>>(rs0, rs1, rs2, cs0, cs1, cs2,
                                     bias[0], bias[1], bias[2],
                                     rw[0], rw[1], rw[2], rb[0], rb[1], rb[2],
                                     cw[0], cw[1], cw[2], cb[0], cb[1], cb[2],
                                     Lb[0], Lb[1], Lb[2], bw[0], bw[1], bw[2],
                                     bb[0], bb[1], bb[2], rcz, brcz,
                                     rowz0, rowz1, rowz2, colz0, colz1, colz2,
                                     outb0, outb1, outb2);

  k6_all<<<4096, 256, 0, stream>>>(w[0], w[1], w[2],
                                   rowz0, rowz1, rowz2,
                                   colz0, colz1, colz2,
                                   Lw[0], Lw[1], Lw[2],
                                   outw0, outw1, outw2);
}